// Round 8
// baseline (376.522 us; speedup 1.0000x reference)
//
#include <hip/hip_runtime.h>

#define DD 64
constexpr float BETA  = 0.2f;
constexpr float GAMMA = 0.95f;

typedef float f4 __attribute__((ext_vector_type(4)));

// ---------- Pass 1: per-node row max (4 nodes per wave) + zero counts ----------
__global__ void zmax_kernel(const float* __restrict__ z, float* __restrict__ zmax,
                            int* __restrict__ counts, int n) {
    int wid  = blockIdx.x * (blockDim.x >> 6) + (threadIdx.x >> 6);
    int lane = threadIdx.x & 63;
    int r = lane >> 4;          // node within wave's group of 4
    int c = lane & 15;          // float4 index within row
    int node = wid * 4 + r;
    if (node >= n) return;
    f4 v = ((const f4*)(z + (long)node * DD))[c];
    float m = fmaxf(fmaxf(v.x, v.y), fmaxf(v.z, v.w));
    #pragma unroll
    for (int off = 1; off < 16; off <<= 1)
        m = fmaxf(m, __shfl_xor(m, off, 64));
    if (c == 0) { zmax[node] = m; counts[node] = 0; }
}

// ---------- Pass 2a: histogram of dst + zmq = gamma*zmax[src] (4 edges/thread) ----------
__global__ void hist_zmq_kernel(const int* __restrict__ dst, const int* __restrict__ src,
                                const float* __restrict__ zmax,
                                int* __restrict__ counts, float* __restrict__ zmq, int nE) {
    int i = (blockIdx.x * blockDim.x + threadIdx.x) * 4;
    if (i + 3 < nE) {
        int4 d = *(const int4*)(dst + i);
        atomicAdd(&counts[d.x], 1); atomicAdd(&counts[d.y], 1);
        atomicAdd(&counts[d.z], 1); atomicAdd(&counts[d.w], 1);
        int4 s = *(const int4*)(src + i);
        f4 q;
        q.x = GAMMA * zmax[s.x]; q.y = GAMMA * zmax[s.y];
        q.z = GAMMA * zmax[s.z]; q.w = GAMMA * zmax[s.w];
        *(f4*)(zmq + i) = q;
    } else {
        for (int j = i; j < nE; j++) {
            atomicAdd(&counts[dst[j]], 1);
            zmq[j] = GAMMA * zmax[src[j]];
        }
    }
}

// ---------- Pass 2b: block-local exclusive scan (1024 elems / 256-thread block) ----------
__global__ void scan_local_kernel(const int* __restrict__ counts, int* __restrict__ base,
                                  int* __restrict__ bsums, int n) {
    __shared__ int warp_sums[4];
    int t = threadIdx.x;
    int lane = t & 63, w = t >> 6;
    int g0 = blockIdx.x * 1024 + t * 4;
    int c[4];
    int s = 0;
    #pragma unroll
    for (int j = 0; j < 4; j++) {
        c[j] = (g0 + j < n) ? counts[g0 + j] : 0;
        s += c[j];
    }
    int v = s;
    #pragma unroll
    for (int off = 1; off < 64; off <<= 1) {
        int u = __shfl_up(v, off, 64);
        if (lane >= off) v += u;
    }
    if (lane == 63) warp_sums[w] = v;
    __syncthreads();
    int wo = 0;
    for (int k = 0; k < w; k++) wo += warp_sums[k];
    int acc = wo + v - s;
    #pragma unroll
    for (int j = 0; j < 4; j++) {
        if (g0 + j < n) base[g0 + j] = acc;
        acc += c[j];
    }
    if (t == 255) bsums[blockIdx.x] = wo + v;
}

// ---------- Pass 2c: scan the (<=256) block sums ----------
__global__ void scan_bsums_kernel(int* __restrict__ bsums, int nb) {
    __shared__ int warp_sums[4];
    int t = threadIdx.x, lane = t & 63, w = t >> 6;
    int s = (t < nb) ? bsums[t] : 0;
    int v = s;
    #pragma unroll
    for (int off = 1; off < 64; off <<= 1) {
        int u = __shfl_up(v, off, 64);
        if (lane >= off) v += u;
    }
    if (lane == 63) warp_sums[w] = v;
    __syncthreads();
    int wo = 0;
    for (int k = 0; k < w; k++) wo += warp_sums[k];
    if (t < nb) bsums[t] = wo + v - s;
}

// ---------- Pass 2d: add block offsets; init cursor ----------
__global__ void add_off_kernel(int* __restrict__ base, int* __restrict__ cursor,
                               const int* __restrict__ bsums, int n) {
    int i = blockIdx.x * blockDim.x + threadIdx.x;
    if (i >= n) return;
    int b = base[i] + bsums[i >> 10];
    base[i] = b;
    cursor[i] = b;
}

// ---------- Pass 2e: scatter packed {eid, zmq} into CSR order (4 edges/thread) ----------
// One int2 (8B) random write per edge instead of two 4B writes to arrays 12.8MB
// apart -> half the 64B-line write-allocate traffic.
__global__ void scatter_kernel(const int* __restrict__ dst, const float* __restrict__ zmq,
                               int* __restrict__ cursor, int2* __restrict__ pk, int nE) {
    int i = (blockIdx.x * blockDim.x + threadIdx.x) * 4;
    if (i + 3 < nE) {
        int4 d = *(const int4*)(dst + i);
        f4 q = *(const f4*)(zmq + i);
        int p0 = atomicAdd(&cursor[d.x], 1);
        int p1 = atomicAdd(&cursor[d.y], 1);
        int p2 = atomicAdd(&cursor[d.z], 1);
        int p3 = atomicAdd(&cursor[d.w], 1);
        pk[p0] = make_int2(i,     __float_as_int(q.x));
        pk[p1] = make_int2(i + 1, __float_as_int(q.y));
        pk[p2] = make_int2(i + 2, __float_as_int(q.z));
        pk[p3] = make_int2(i + 3, __float_as_int(q.w));
    } else {
        for (int j = i; j < nE; j++) {
            int p = atomicAdd(&cursor[dst[j]], 1);
            pk[p] = make_int2(j, __float_as_int(zmq[j]));
        }
    }
}

// ---------- Pass 3: gather + finalize (one wave per node, 4-deep load pipeline) ----------
// Lane layout: lane = 32*p + c, p in {0,1}, c in [0,32). Lane loads float4 #c of
// edge (2t+p)'s 512B row: c<16 -> e0 quarters, c>=16 -> e1 quarters.
__global__ void gather_kernel(const float* __restrict__ z,
                              const float* __restrict__ e,
                              const int* __restrict__ base,
                              const int* __restrict__ counts,
                              const int2* __restrict__ pk,
                              float* __restrict__ out, int n) {
    int node = blockIdx.x * (blockDim.x >> 6) + (threadIdx.x >> 6);
    int lane = threadIdx.x & 63;
    if (node >= n) return;
    int c = lane & 31;
    int p = lane >> 5;

    f4 zi = ((const f4*)(z + (long)node * DD))[lane & 15];

    int degv = counts[node];
    if (degv == 0) {
        if (lane < 16) ((f4*)(out + (long)node * DD))[lane] = zi;
        return;
    }
    int start = base[node];

    float a1x = 0, a1y = 0, a1z = 0, a1w = 0;   // sum of w  * v
    float a2x = 0, a2y = 0, a2z = 0, a2w = 0;   // sum of zm * v

    int done = 0;
    while (done < degv) {
        int batch = min(degv - done, 64);
        int2 pv = make_int2(0, 0);
        if (lane < batch) pv = pk[start + done + lane];
        int   eidv = pv.x;
        float zmv  = __int_as_float(pv.y);   // 0.0f for lanes >= batch

        int npair = (batch + 1) >> 1;
        int t = 0;
        for (; t + 4 <= npair; t += 4) {
            int k0 = 2 * t + p, k1 = k0 + 2, k2 = k0 + 4, k3 = k0 + 6;
            int eid0 = __shfl(eidv, k0, 64);
            int eid1 = __shfl(eidv, k1, 64);
            int eid2 = __shfl(eidv, k2, 64);
            int eid3 = __shfl(eidv, k3, 64);
            f4 v0 = __builtin_nontemporal_load((const f4*)(e + (long)eid0 * (2 * DD)) + c);
            f4 v1 = __builtin_nontemporal_load((const f4*)(e + (long)eid1 * (2 * DD)) + c);
            f4 v2 = __builtin_nontemporal_load((const f4*)(e + (long)eid2 * (2 * DD)) + c);
            f4 v3 = __builtin_nontemporal_load((const f4*)(e + (long)eid3 * (2 * DD)) + c);
            float zm0 = __shfl(zmv, k0, 64);
            float zm1 = __shfl(zmv, k1, 64);
            float zm2 = __shfl(zmv, k2, 64);
            float zm3 = __shfl(zmv, k3, 64);
            float w0 = (k0 < batch) ? 1.0f : 0.0f;
            float w1 = (k1 < batch) ? 1.0f : 0.0f;
            float w2 = (k2 < batch) ? 1.0f : 0.0f;
            float w3 = (k3 < batch) ? 1.0f : 0.0f;
            a1x = fmaf(w0, v0.x, a1x); a1y = fmaf(w0, v0.y, a1y);
            a1z = fmaf(w0, v0.z, a1z); a1w = fmaf(w0, v0.w, a1w);
            a2x = fmaf(zm0, v0.x, a2x); a2y = fmaf(zm0, v0.y, a2y);
            a2z = fmaf(zm0, v0.z, a2z); a2w = fmaf(zm0, v0.w, a2w);
            a1x = fmaf(w1, v1.x, a1x); a1y = fmaf(w1, v1.y, a1y);
            a1z = fmaf(w1, v1.z, a1z); a1w = fmaf(w1, v1.w, a1w);
            a2x = fmaf(zm1, v1.x, a2x); a2y = fmaf(zm1, v1.y, a2y);
            a2z = fmaf(zm1, v1.z, a2z); a2w = fmaf(zm1, v1.w, a2w);
            a1x = fmaf(w2, v2.x, a1x); a1y = fmaf(w2, v2.y, a1y);
            a1z = fmaf(w2, v2.z, a1z); a1w = fmaf(w2, v2.w, a1w);
            a2x = fmaf(zm2, v2.x, a2x); a2y = fmaf(zm2, v2.y, a2y);
            a2z = fmaf(zm2, v2.z, a2z); a2w = fmaf(zm2, v2.w, a2w);
            a1x = fmaf(w3, v3.x, a1x); a1y = fmaf(w3, v3.y, a1y);
            a1z = fmaf(w3, v3.z, a1z); a1w = fmaf(w3, v3.w, a1w);
            a2x = fmaf(zm3, v3.x, a2x); a2y = fmaf(zm3, v3.y, a2y);
            a2z = fmaf(zm3, v3.z, a2z); a2w = fmaf(zm3, v3.w, a2w);
        }
        for (; t < npair; t++) {
            int k = 2 * t + p;
            int   eid = __shfl(eidv, k, 64);
            float zm  = __shfl(zmv, k, 64);
            float w   = (k < batch) ? 1.0f : 0.0f;
            f4 v = __builtin_nontemporal_load((const f4*)(e + (long)eid * (2 * DD)) + c);
            a1x = fmaf(w, v.x, a1x); a1y = fmaf(w, v.y, a1y);
            a1z = fmaf(w, v.z, a1z); a1w = fmaf(w, v.w, a1w);
            a2x = fmaf(zm, v.x, a2x); a2y = fmaf(zm, v.y, a2y);
            a2z = fmaf(zm, v.z, a2z); a2w = fmaf(zm, v.w, a2w);
        }
        done += batch;
    }

    // Combine p halves.
    a1x += __shfl_xor(a1x, 32, 64); a1y += __shfl_xor(a1y, 32, 64);
    a1z += __shfl_xor(a1z, 32, 64); a1w += __shfl_xor(a1w, 32, 64);
    a2x += __shfl_xor(a2x, 32, 64); a2y += __shfl_xor(a2y, 32, 64);
    a2z += __shfl_xor(a2z, 32, 64); a2w += __shfl_xor(a2w, 32, 64);

    // Lane c<16 holds sum(e0) in a1; partner lane c+16 holds sum(e1) in a1
    // and sum(zm*e1) in a2.
    int pl = (lane & 15) + 16;
    float sax = __shfl(a1x, pl, 64), say = __shfl(a1y, pl, 64);
    float saz = __shfl(a1z, pl, 64), saw = __shfl(a1w, pl, 64);
    float sqx = a1x + __shfl(a2x, pl, 64);
    float sqy = a1y + __shfl(a2y, pl, 64);
    float sqz = a1z + __shfl(a2z, pl, 64);
    float sqw = a1w + __shfl(a2w, pl, 64);

    if (lane < 16) {
        const float ob = 1.0f - BETA;
        f4 r;
        r.x = fmaf(BETA, zi.x, ob * sqx / (sax + 1e-6f));
        r.y = fmaf(BETA, zi.y, ob * sqy / (say + 1e-6f));
        r.z = fmaf(BETA, zi.z, ob * sqz / (saz + 1e-6f));
        r.w = fmaf(BETA, zi.w, ob * sqw / (saw + 1e-6f));
        ((f4*)(out + (long)node * DD))[lane] = r;
    }
}

extern "C" void kernel_launch(void* const* d_in, const int* in_sizes, int n_in,
                              void* d_out, int out_size, void* d_ws, size_t ws_size,
                              hipStream_t stream) {
    const float* z   = (const float*)d_in[0];
    const float* e   = (const float*)d_in[1];
    const int*   src = (const int*)d_in[2];
    const int*   dst = (const int*)d_in[3];
    float* out = (float*)d_out;

    int n  = in_sizes[0] / DD;   // 100000
    int nE = in_sizes[2];        // 1600000
    int nb = (n + 1023) / 1024;  // scan blocks (98)

    char* ws = (char*)d_ws;
    size_t off = 0;
    auto alloc = [&](size_t bytes) { void* q = ws + off; off = (off + bytes + 255) & ~255ull; return q; };
    float* zmax = (float*)alloc((size_t)n * 4);
    int* counts = (int*)alloc((size_t)n * 4);
    int* base   = (int*)alloc((size_t)n * 4);
    int* cursor = (int*)alloc((size_t)n * 4);
    int* bsums  = (int*)alloc((size_t)nb * 4);
    float* zmq  = (float*)alloc((size_t)nE * 4);
    int2* pk    = (int2*)alloc((size_t)nE * 8);

    // 1. zmax + counts=0 (4 nodes per wave)
    zmax_kernel<<<(n + 15) / 16, 256, 0, stream>>>(z, zmax, counts, n);
    // 2. CSR build (hist fused with zmq precompute)
    hist_zmq_kernel<<<(nE / 4 + 255) / 256, 256, 0, stream>>>(dst, src, zmax, counts, zmq, nE);
    scan_local_kernel<<<nb, 256, 0, stream>>>(counts, base, bsums, n);
    scan_bsums_kernel<<<1, 256, 0, stream>>>(bsums, nb);
    add_off_kernel<<<(n + 255) / 256, 256, 0, stream>>>(base, cursor, bsums, n);
    scatter_kernel<<<(nE / 4 + 255) / 256, 256, 0, stream>>>(dst, zmq, cursor, pk, nE);
    // 3. gather + finalize
    gather_kernel<<<(n + 3) / 4, 256, 0, stream>>>(z, e, base, counts, pk, out, n);
}

// Round 9
// 346.847 us; speedup vs baseline: 1.0856x; 1.0856x over previous
//
#include <hip/hip_runtime.h>

#define DD 64
constexpr float BETA  = 0.2f;
constexpr float GAMMA = 0.95f;

typedef float f4 __attribute__((ext_vector_type(4)));

// ---------- Pass 1: per-node row max (4 nodes per wave) + zero counts ----------
__global__ void zmax_kernel(const float* __restrict__ z, float* __restrict__ zmax,
                            int* __restrict__ counts, int n) {
    int wid  = blockIdx.x * (blockDim.x >> 6) + (threadIdx.x >> 6);
    int lane = threadIdx.x & 63;
    int r = lane >> 4;          // node within wave's group of 4
    int c = lane & 15;          // float4 index within row
    int node = wid * 4 + r;
    if (node >= n) return;
    f4 v = ((const f4*)(z + (long)node * DD))[c];
    float m = fmaxf(fmaxf(v.x, v.y), fmaxf(v.z, v.w));
    #pragma unroll
    for (int off = 1; off < 16; off <<= 1)
        m = fmaxf(m, __shfl_xor(m, off, 64));
    if (c == 0) { zmax[node] = m; counts[node] = 0; }
}

// ---------- Pass 2a: histogram of dst + zmq = gamma*zmax[src] (4 edges/thread) ----------
__global__ void hist_zmq_kernel(const int* __restrict__ dst, const int* __restrict__ src,
                                const float* __restrict__ zmax,
                                int* __restrict__ counts, float* __restrict__ zmq, int nE) {
    int i = (blockIdx.x * blockDim.x + threadIdx.x) * 4;
    if (i + 3 < nE) {
        int4 d = *(const int4*)(dst + i);
        atomicAdd(&counts[d.x], 1); atomicAdd(&counts[d.y], 1);
        atomicAdd(&counts[d.z], 1); atomicAdd(&counts[d.w], 1);
        int4 s = *(const int4*)(src + i);
        f4 q;
        q.x = GAMMA * zmax[s.x]; q.y = GAMMA * zmax[s.y];
        q.z = GAMMA * zmax[s.z]; q.w = GAMMA * zmax[s.w];
        *(f4*)(zmq + i) = q;
    } else {
        for (int j = i; j < nE; j++) {
            atomicAdd(&counts[dst[j]], 1);
            zmq[j] = GAMMA * zmax[src[j]];
        }
    }
}

// ---------- Pass 2b: block-local exclusive scan (1024 elems / 256-thread block) ----------
__global__ void scan_local_kernel(const int* __restrict__ counts, int* __restrict__ base,
                                  int* __restrict__ bsums, int n) {
    __shared__ int warp_sums[4];
    int t = threadIdx.x;
    int lane = t & 63, w = t >> 6;
    int g0 = blockIdx.x * 1024 + t * 4;
    int c[4];
    int s = 0;
    #pragma unroll
    for (int j = 0; j < 4; j++) {
        c[j] = (g0 + j < n) ? counts[g0 + j] : 0;
        s += c[j];
    }
    int v = s;
    #pragma unroll
    for (int off = 1; off < 64; off <<= 1) {
        int u = __shfl_up(v, off, 64);
        if (lane >= off) v += u;
    }
    if (lane == 63) warp_sums[w] = v;
    __syncthreads();
    int wo = 0;
    for (int k = 0; k < w; k++) wo += warp_sums[k];
    int acc = wo + v - s;
    #pragma unroll
    for (int j = 0; j < 4; j++) {
        if (g0 + j < n) base[g0 + j] = acc;
        acc += c[j];
    }
    if (t == 255) bsums[blockIdx.x] = wo + v;   // RAW block total (no second scan pass)
}

// ---------- Pass 2c: add block offsets (redundant per-block reduce of raw bsums) ----------
// All 256 threads of a block share the same i>>10, so each wave redundantly
// sums bsums[0 .. g) (g <= 98, L2-hit) and adds it -- replaces the separate
// scan_bsums launch.
__global__ void add_off_kernel(int* __restrict__ base, int* __restrict__ cursor,
                               const int* __restrict__ bsums, int n) {
    int i = blockIdx.x * blockDim.x + threadIdx.x;
    int g = (blockIdx.x * blockDim.x) >> 10;   // uniform across block
    int lane = threadIdx.x & 63;
    int s = 0;
    for (int k = lane; k < g; k += 64) s += bsums[k];
    #pragma unroll
    for (int off = 32; off > 0; off >>= 1) s += __shfl_xor(s, off, 64);
    if (i >= n) return;
    int b = base[i] + s;
    base[i] = b;
    cursor[i] = b;
}

// ---------- Pass 2e: scatter edge ids + zmq into CSR order (4 edges/thread) ----------
__global__ void scatter_kernel(const int* __restrict__ dst, const float* __restrict__ zmq,
                               int* __restrict__ cursor,
                               int* __restrict__ perm, float* __restrict__ zmq_csr, int nE) {
    int i = (blockIdx.x * blockDim.x + threadIdx.x) * 4;
    if (i + 3 < nE) {
        int4 d = *(const int4*)(dst + i);
        f4 q = *(const f4*)(zmq + i);
        int p0 = atomicAdd(&cursor[d.x], 1);
        int p1 = atomicAdd(&cursor[d.y], 1);
        int p2 = atomicAdd(&cursor[d.z], 1);
        int p3 = atomicAdd(&cursor[d.w], 1);
        perm[p0] = i;     zmq_csr[p0] = q.x;
        perm[p1] = i + 1; zmq_csr[p1] = q.y;
        perm[p2] = i + 2; zmq_csr[p2] = q.z;
        perm[p3] = i + 3; zmq_csr[p3] = q.w;
    } else {
        for (int j = i; j < nE; j++) {
            int p = atomicAdd(&cursor[dst[j]], 1);
            perm[p] = j; zmq_csr[p] = zmq[j];
        }
    }
}

// ---------- Pass 3: gather + finalize (one wave per node, 4-deep load pipeline) ----------
// Lane layout: lane = 32*p + c, p in {0,1}, c in [0,32). Lane loads float4 #c of
// edge (2t+p)'s 512B row: c<16 -> e0 quarters, c>=16 -> e1 quarters.
__global__ void gather_kernel(const float* __restrict__ z,
                              const float* __restrict__ e,
                              const int* __restrict__ base,
                              const int* __restrict__ counts,
                              const int* __restrict__ perm,
                              const float* __restrict__ zmq_csr,
                              float* __restrict__ out, int n) {
    int node = blockIdx.x * (blockDim.x >> 6) + (threadIdx.x >> 6);
    int lane = threadIdx.x & 63;
    if (node >= n) return;
    int c = lane & 31;
    int p = lane >> 5;

    f4 zi = ((const f4*)(z + (long)node * DD))[lane & 15];

    int degv = counts[node];
    if (degv == 0) {
        if (lane < 16) ((f4*)(out + (long)node * DD))[lane] = zi;
        return;
    }
    int start = base[node];

    float a1x = 0, a1y = 0, a1z = 0, a1w = 0;   // sum of w  * v
    float a2x = 0, a2y = 0, a2z = 0, a2w = 0;   // sum of zm * v

    int done = 0;
    while (done < degv) {
        int batch = min(degv - done, 64);
        int eidv = 0; float zmv = 0.0f;
        if (lane < batch) {
            eidv = __builtin_nontemporal_load(perm + start + done + lane);
            zmv  = __builtin_nontemporal_load(zmq_csr + start + done + lane);
        }
        int npair = (batch + 1) >> 1;
        int t = 0;
        for (; t + 4 <= npair; t += 4) {
            int k0 = 2 * t + p, k1 = k0 + 2, k2 = k0 + 4, k3 = k0 + 6;
            int eid0 = __shfl(eidv, k0, 64);
            int eid1 = __shfl(eidv, k1, 64);
            int eid2 = __shfl(eidv, k2, 64);
            int eid3 = __shfl(eidv, k3, 64);
            f4 v0 = __builtin_nontemporal_load((const f4*)(e + (long)eid0 * (2 * DD)) + c);
            f4 v1 = __builtin_nontemporal_load((const f4*)(e + (long)eid1 * (2 * DD)) + c);
            f4 v2 = __builtin_nontemporal_load((const f4*)(e + (long)eid2 * (2 * DD)) + c);
            f4 v3 = __builtin_nontemporal_load((const f4*)(e + (long)eid3 * (2 * DD)) + c);
            float zm0 = __shfl(zmv, k0, 64);
            float zm1 = __shfl(zmv, k1, 64);
            float zm2 = __shfl(zmv, k2, 64);
            float zm3 = __shfl(zmv, k3, 64);
            float w0 = (k0 < batch) ? 1.0f : 0.0f;
            float w1 = (k1 < batch) ? 1.0f : 0.0f;
            float w2 = (k2 < batch) ? 1.0f : 0.0f;
            float w3 = (k3 < batch) ? 1.0f : 0.0f;
            a1x = fmaf(w0, v0.x, a1x); a1y = fmaf(w0, v0.y, a1y);
            a1z = fmaf(w0, v0.z, a1z); a1w = fmaf(w0, v0.w, a1w);
            a2x = fmaf(zm0, v0.x, a2x); a2y = fmaf(zm0, v0.y, a2y);
            a2z = fmaf(zm0, v0.z, a2z); a2w = fmaf(zm0, v0.w, a2w);
            a1x = fmaf(w1, v1.x, a1x); a1y = fmaf(w1, v1.y, a1y);
            a1z = fmaf(w1, v1.z, a1z); a1w = fmaf(w1, v1.w, a1w);
            a2x = fmaf(zm1, v1.x, a2x); a2y = fmaf(zm1, v1.y, a2y);
            a2z = fmaf(zm1, v1.z, a2z); a2w = fmaf(zm1, v1.w, a2w);
            a1x = fmaf(w2, v2.x, a1x); a1y = fmaf(w2, v2.y, a1y);
            a1z = fmaf(w2, v2.z, a1z); a1w = fmaf(w2, v2.w, a1w);
            a2x = fmaf(zm2, v2.x, a2x); a2y = fmaf(zm2, v2.y, a2y);
            a2z = fmaf(zm2, v2.z, a2z); a2w = fmaf(zm2, v2.w, a2w);
            a1x = fmaf(w3, v3.x, a1x); a1y = fmaf(w3, v3.y, a1y);
            a1z = fmaf(w3, v3.z, a1z); a1w = fmaf(w3, v3.w, a1w);
            a2x = fmaf(zm3, v3.x, a2x); a2y = fmaf(zm3, v3.y, a2y);
            a2z = fmaf(zm3, v3.z, a2z); a2w = fmaf(zm3, v3.w, a2w);
        }
        for (; t < npair; t++) {
            int k = 2 * t + p;
            int   eid = __shfl(eidv, k, 64);
            float zm  = __shfl(zmv, k, 64);
            float w   = (k < batch) ? 1.0f : 0.0f;
            f4 v = __builtin_nontemporal_load((const f4*)(e + (long)eid * (2 * DD)) + c);
            a1x = fmaf(w, v.x, a1x); a1y = fmaf(w, v.y, a1y);
            a1z = fmaf(w, v.z, a1z); a1w = fmaf(w, v.w, a1w);
            a2x = fmaf(zm, v.x, a2x); a2y = fmaf(zm, v.y, a2y);
            a2z = fmaf(zm, v.z, a2z); a2w = fmaf(zm, v.w, a2w);
        }
        done += batch;
    }

    // Combine p halves.
    a1x += __shfl_xor(a1x, 32, 64); a1y += __shfl_xor(a1y, 32, 64);
    a1z += __shfl_xor(a1z, 32, 64); a1w += __shfl_xor(a1w, 32, 64);
    a2x += __shfl_xor(a2x, 32, 64); a2y += __shfl_xor(a2y, 32, 64);
    a2z += __shfl_xor(a2z, 32, 64); a2w += __shfl_xor(a2w, 32, 64);

    // Lane c<16 holds sum(e0) in a1; partner lane c+16 holds sum(e1) in a1
    // and sum(zm*e1) in a2.
    int pl = (lane & 15) + 16;
    float sax = __shfl(a1x, pl, 64), say = __shfl(a1y, pl, 64);
    float saz = __shfl(a1z, pl, 64), saw = __shfl(a1w, pl, 64);
    float sqx = a1x + __shfl(a2x, pl, 64);
    float sqy = a1y + __shfl(a2y, pl, 64);
    float sqz = a1z + __shfl(a2z, pl, 64);
    float sqw = a1w + __shfl(a2w, pl, 64);

    if (lane < 16) {
        const float ob = 1.0f - BETA;
        f4 r;
        r.x = fmaf(BETA, zi.x, ob * sqx / (sax + 1e-6f));
        r.y = fmaf(BETA, zi.y, ob * sqy / (say + 1e-6f));
        r.z = fmaf(BETA, zi.z, ob * sqz / (saz + 1e-6f));
        r.w = fmaf(BETA, zi.w, ob * sqw / (saw + 1e-6f));
        ((f4*)(out + (long)node * DD))[lane] = r;
    }
}

extern "C" void kernel_launch(void* const* d_in, const int* in_sizes, int n_in,
                              void* d_out, int out_size, void* d_ws, size_t ws_size,
                              hipStream_t stream) {
    const float* z   = (const float*)d_in[0];
    const float* e   = (const float*)d_in[1];
    const int*   src = (const int*)d_in[2];
    const int*   dst = (const int*)d_in[3];
    float* out = (float*)d_out;

    int n  = in_sizes[0] / DD;   // 100000
    int nE = in_sizes[2];        // 1600000
    int nb = (n + 1023) / 1024;  // scan blocks (98)

    char* ws = (char*)d_ws;
    size_t off = 0;
    auto alloc = [&](size_t bytes) { void* q = ws + off; off = (off + bytes + 255) & ~255ull; return q; };
    float* zmax    = (float*)alloc((size_t)n * 4);
    int* counts    = (int*)alloc((size_t)n * 4);
    int* base      = (int*)alloc((size_t)n * 4);
    int* cursor    = (int*)alloc((size_t)n * 4);
    int* bsums     = (int*)alloc((size_t)nb * 4);
    int* perm      = (int*)alloc((size_t)nE * 4);
    float* zmq     = (float*)alloc((size_t)nE * 4);
    float* zmq_csr = (float*)alloc((size_t)nE * 4);

    // 1. zmax + counts=0 (4 nodes per wave)
    zmax_kernel<<<(n + 15) / 16, 256, 0, stream>>>(z, zmax, counts, n);
    // 2. CSR build (hist fused with zmq precompute; bsums scan folded into add_off)
    hist_zmq_kernel<<<(nE / 4 + 255) / 256, 256, 0, stream>>>(dst, src, zmax, counts, zmq, nE);
    scan_local_kernel<<<nb, 256, 0, stream>>>(counts, base, bsums, n);
    add_off_kernel<<<(n + 255) / 256, 256, 0, stream>>>(base, cursor, bsums, n);
    scatter_kernel<<<(nE / 4 + 255) / 256, 256, 0, stream>>>(dst, zmq, cursor, perm, zmq_csr, nE);
    // 3. gather + finalize
    gather_kernel<<<(n + 3) / 4, 256, 0, stream>>>(z, e, base, counts, perm, zmq_csr, out, n);
}